// Round 1
// baseline (1124.179 us; speedup 1.0000x reference)
//
#include <hip/hip_runtime.h>

#define NN 50000
#define NE 800000
#define BG 512
#define HD 128
#define GD 32
#define MD 128
#define EPSV 1e-5f
#define NBK 256   // dst buckets
#define BSTR 196  // dst per bucket
#define BCAP 4096 // edge capacity per bucket
#define SP 136    // LDS row stride (shorts) for gemm tiles
#define GRID 512  // persistent blocks: 2/CU * 256 CU, co-residency guaranteed
#define BINB 391  // (NE+2047)/2048
#define GEMMV 782 // (NN+63)/64
#define AGGV 12500 // (NN+3)/4
#define POOLV 782
#define SMEMB 53248 // union LDS: gemm phase is max (17408+34816+1024)

typedef __attribute__((ext_vector_type(8))) short bf16x8;
typedef __attribute__((ext_vector_type(4))) float f32x4;

static __device__ __forceinline__ unsigned short f2bf(float f) {
    unsigned int u = __float_as_uint(f);
    u += 0x7fffu + ((u >> 16) & 1u);
    return (unsigned short)(u >> 16);
}
static __device__ __forceinline__ float bfu(unsigned short v) {
    return __uint_as_float((unsigned int)v << 16);
}
static __device__ __forceinline__ float bf_lo(unsigned int v) {
    return __uint_as_float(v << 16);
}
static __device__ __forceinline__ float bf_hi(unsigned int v) {
    return __uint_as_float(v & 0xffff0000u);
}

// ---------------- init: zero accumulators + grid barrier ----------------
__global__ __launch_bounds__(256) void k_init(int* bucket_cnt, float* pooled,
                                              float* stats, unsigned* bar) {
    int idx = blockIdx.x * 256 + threadIdx.x;
    if (idx < NBK) bucket_cnt[idx] = 0;
    if (idx < BG * HD) pooled[idx] = 0.f;
    if (idx < 768) stats[idx] = 0.f;
    if (idx < 2) bar[idx] = 0u;
}

// ---------------- device-scope grid barrier (sense via generation ctr) ----------------
// thread0's __threadfence emits buffer_wbl2 (release: flushes the whole XCD L2,
// covering all blockmates' writes) / buffer_inv (acquire) -> safe across XCDs (G16).
static __device__ __forceinline__ void gsync(unsigned* bar) {
    __syncthreads();
    if (threadIdx.x == 0) {
        __threadfence();
        unsigned g = __hip_atomic_load(&bar[1], __ATOMIC_RELAXED, __HIP_MEMORY_SCOPE_AGENT);
        unsigned a = __hip_atomic_fetch_add(&bar[0], 1u, __ATOMIC_ACQ_REL, __HIP_MEMORY_SCOPE_AGENT);
        if (a == GRID - 1) {
            __hip_atomic_store(&bar[0], 0u, __ATOMIC_RELAXED, __HIP_MEMORY_SCOPE_AGENT);
            __hip_atomic_store(&bar[1], g + 1u, __ATOMIC_RELEASE, __HIP_MEMORY_SCOPE_AGENT);
        } else {
            while (__hip_atomic_load(&bar[1], __ATOMIC_RELAXED, __HIP_MEMORY_SCOPE_AGENT) == g)
                __builtin_amdgcn_s_sleep(4);
        }
        __threadfence();
    }
    __syncthreads();
}

// ---------------- phase: bin edges by dst bucket ----------------
static __device__ __forceinline__ void bin_body(int vb, const int* src, const int* dst,
                                                int* bucket_cnt, unsigned* binned,
                                                char* smem) {
    int* hcnt = (int*)smem;
    int* hbase = (int*)(smem + 1024);
    int tid = threadIdx.x;
    int e0 = vb * 2048;
    unsigned pv[8];
    int bk[8], rk[8];
#pragma unroll
    for (int i = 0; i < 8; ++i) {
        int e = e0 + i * 256 + tid;
        if (e < NE) {
            int s = src[e];
            int d = dst[e];
            bk[i] = d / BSTR;
            pv[i] = ((unsigned)(d - bk[i] * BSTR) << 16) | (unsigned)s;
        } else {
            bk[i] = -1;
        }
    }
    hcnt[tid] = 0;
    __syncthreads();
#pragma unroll
    for (int i = 0; i < 8; ++i)
        if (bk[i] >= 0) rk[i] = atomicAdd(&hcnt[bk[i]], 1);
    __syncthreads();
    hbase[tid] = atomicAdd(&bucket_cnt[tid], hcnt[tid]);
    __syncthreads();
#pragma unroll
    for (int i = 0; i < 8; ++i)
        if (bk[i] >= 0)
            binned[(size_t)bk[i] * BCAP + hbase[bk[i]] + rk[i]] = pv[i];
}

// ---------------- phase: CSR build (vb 0..255) + W transpose (vb 256..258) ----------------
static __device__ __forceinline__ void csr_body(int b, const unsigned* binned,
                                                const int* bucket_cnt, int* offsets,
                                                float* dinv, int* csr,
                                                const float* W0, const float* W1,
                                                const float* W2, unsigned short* Wt,
                                                char* smem) {
    int t = threadIdx.x;
    if (b >= NBK) {
        unsigned short* sW = (unsigned short*)smem;  // 128*130 shorts = 33280 B
        const float* Wsrc = (b == NBK) ? W0 : ((b == NBK + 1) ? W1 : W2);
#pragma unroll
        for (int i = 0; i < 64; ++i) {
            int idx = i * 256 + t;
            int k = idx >> 7, n = idx & 127;
            sW[n * 130 + k] = f2bf(Wsrc[idx]);
        }
        __syncthreads();
        unsigned short* o = Wt + (size_t)(b - NBK) * 16384;
#pragma unroll
        for (int i = 0; i < 64; ++i) {
            int idx = i * 256 + t;
            int n = idx >> 7, k = idx & 127;
            o[idx] = sW[n * 130 + k];
        }
        return;
    }
    int* ls = (int*)(smem + 33280);
    int* h = ls + 256;
    int* cur = h + BSTR;
    int* bpre = cur + BSTR;
    int bc = bucket_cnt[t];
    ls[t] = bc;
    __syncthreads();
    for (int off = 1; off < 256; off <<= 1) {
        int c0 = ls[t];
        int add = (t >= off) ? ls[t - off] : 0;
        __syncthreads();
        ls[t] = c0 + add;
        __syncthreads();
    }
    if (t == b) bpre[0] = ls[t] - bc;
    if (t < BSTR) h[t] = 0;
    __syncthreads();
    int bpre_v = bpre[0];
    int nb = bucket_cnt[b];
    const unsigned* base = binned + (size_t)b * BCAP;
    for (int e = t; e < nb; e += 256)
        atomicAdd(&h[base[e] >> 16], 1);
    __syncthreads();
    int c = (t < BSTR) ? h[t] : 0;
    ls[t] = c;
    __syncthreads();
    for (int off = 1; off < 256; off <<= 1) {
        int c0 = ls[t];
        int add = (t >= off) ? ls[t - off] : 0;
        __syncthreads();
        ls[t] = c0 + add;
        __syncthreads();
    }
    int node = b * BSTR + t;
    if (t < BSTR) {
        int excl = ls[t] - c + bpre_v;
        cur[t] = excl;
        if (node < NN) {
            offsets[node] = excl;
            dinv[node] = rsqrtf((float)(c + 1));
            if (node == NN - 1) offsets[NN] = NE;
        }
    }
    __syncthreads();
    for (int e = t; e < nb; e += 256) {
        unsigned v = base[e];
        int pos = atomicAdd(&cur[v >> 16], 1);
        csr[pos] = (int)(v & 0xffffu);
    }
}

// ---------------- phase: MFMA GEMM Th = dinv[row] * (BNReLU?(In) @ W) ----------------
static __device__ __forceinline__ void gemm_body(int vb, const float* Inf,
                                                 const unsigned short* Inh,
                                                 const unsigned short* Wtg,
                                                 unsigned short* Th, const float* stats,
                                                 const float* gamma, const float* beta,
                                                 const float* dinv, int useBN,
                                                 char* smem) {
    unsigned short* Abf = (unsigned short*)smem;                       // 64*SP
    unsigned short* WtL = (unsigned short*)(smem + 64 * SP * 2);       // 128*SP
    float* ssS = (float*)(smem + 64 * SP * 2 + 128 * SP * 2);          // 256 f
    int tid = threadIdx.x;
    int rowBase = vb * 64;
    __syncthreads();  // protect LDS reuse across virtual-block iterations
    if (useBN) {
        ssS[tid] = stats[tid];
        __syncthreads();
        if (tid < 128) {
            float mu = ssS[tid] * (1.f / NN);
            float var = ssS[128 + tid] * (1.f / NN) - mu * mu;
            float sc = gamma[tid] * rsqrtf(var + EPSV);
            float sh = beta[tid] - mu * sc;
            ssS[tid] = sc;
            ssS[128 + tid] = sh;
        }
        __syncthreads();
#pragma unroll
        for (int i = 0; i < 4; ++i) {
            int q = tid + i * 256;
            int row = q >> 4;
            int k8 = (q & 15) * 8;
            int rg = rowBase + row;
            if (rg >= NN) rg = NN - 1;
            bf16x8 raw = *(const bf16x8*)&Inh[(size_t)rg * HD + k8];
            unsigned short o[8];
#pragma unroll
            for (int e = 0; e < 8; ++e) {
                float v = bfu((unsigned short)raw[e]);
                v = fmaxf(v * ssS[k8 + e] + ssS[128 + k8 + e], 0.f);
                o[e] = f2bf(v);
            }
            *(bf16x8*)&Abf[row * SP + k8] = *(bf16x8*)o;
        }
    } else {
#pragma unroll
        for (int i = 0; i < 8; ++i) {
            int q = tid + i * 256;
            int row = q >> 5;
            int c4 = (q & 31) * 4;
            int rg = rowBase + row;
            if (rg >= NN) rg = NN - 1;
            float4 v = *(const float4*)&Inf[(size_t)rg * HD + c4];
            unsigned short* p = &Abf[row * SP + c4];
            p[0] = f2bf(v.x); p[1] = f2bf(v.y); p[2] = f2bf(v.z); p[3] = f2bf(v.w);
        }
    }
#pragma unroll
    for (int i = 0; i < 8; ++i) {
        int q = tid + i * 256;
        int n = q >> 4;
        int k8 = (q & 15) * 8;
        bf16x8 w = *(const bf16x8*)&Wtg[n * HD + k8];
        *(bf16x8*)&WtL[n * SP + k8] = w;
    }
    __syncthreads();
    int lane = tid & 63;
    int wv = tid >> 6;
    int quad = lane >> 4;
    int lrow = wv * 16 + (lane & 15);
    f32x4 acc[8];
#pragma unroll
    for (int c = 0; c < 8; ++c) acc[c] = (f32x4){0.f, 0.f, 0.f, 0.f};
#pragma unroll
    for (int qk = 0; qk < 4; ++qk) {
        int ko = quad * 8 + qk * 32;
        bf16x8 bfr = *(const bf16x8*)&Abf[lrow * SP + ko];
#pragma unroll
        for (int c = 0; c < 8; ++c) {
            bf16x8 afr = *(const bf16x8*)&WtL[(c * 16 + (lane & 15)) * SP + ko];
            acc[c] = __builtin_amdgcn_mfma_f32_16x16x32_bf16(afr, bfr, acc[c], 0, 0, 0);
        }
    }
    int grow = rowBase + lrow;
    if (grow < NN) {
        float di = dinv[grow];
#pragma unroll
        for (int c = 0; c < 8; ++c) {
            ushort4 o;
            o.x = f2bf(acc[c][0] * di);
            o.y = f2bf(acc[c][1] * di);
            o.z = f2bf(acc[c][2] * di);
            o.w = f2bf(acc[c][3] * di);
            *(ushort4*)&Th[(size_t)grow * HD + c * 16 + quad * 4] = o;
        }
    }
}

// ---------------- phase: aggregate + fused column stats ----------------
static __device__ __forceinline__ void agg_body(int vb, const uint2* T2,
                                                const int* offsets, const int* csr,
                                                const float* dinv, const float* bias,
                                                unsigned short* Ah, f32x4& s4, f32x4& q4) {
    int d = vb * 4 + (threadIdx.x >> 6);
    int l = threadIdx.x & 63;
    int half = l >> 5;
    int li = l & 31;
    if (d >= NN) return;
    int start = offsets[d], end = offsets[d + 1];
    float a0 = 0.f, a1 = 0.f, a2 = 0.f, a3 = 0.f;
    int j = start;
    for (; j + 15 < end; j += 16) {
        int s[8];
        uint2 v[8];
#pragma unroll
        for (int i = 0; i < 8; ++i) s[i] = csr[j + 2 * i + half];
#pragma unroll
        for (int i = 0; i < 8; ++i) v[i] = T2[(size_t)s[i] * 32 + li];
#pragma unroll
        for (int i = 0; i < 8; ++i) {
            a0 += bf_lo(v[i].x); a1 += bf_hi(v[i].x);
            a2 += bf_lo(v[i].y); a3 += bf_hi(v[i].y);
        }
    }
    for (; j + 7 < end; j += 8) {
        int s0 = csr[j + half];
        int s1 = csr[j + 2 + half];
        int s2 = csr[j + 4 + half];
        int s3 = csr[j + 6 + half];
        uint2 v0 = T2[(size_t)s0 * 32 + li];
        uint2 v1 = T2[(size_t)s1 * 32 + li];
        uint2 v2 = T2[(size_t)s2 * 32 + li];
        uint2 v3 = T2[(size_t)s3 * 32 + li];
        a0 += bf_lo(v0.x); a1 += bf_hi(v0.x); a2 += bf_lo(v0.y); a3 += bf_hi(v0.y);
        a0 += bf_lo(v1.x); a1 += bf_hi(v1.x); a2 += bf_lo(v1.y); a3 += bf_hi(v1.y);
        a0 += bf_lo(v2.x); a1 += bf_hi(v2.x); a2 += bf_lo(v2.y); a3 += bf_hi(v2.y);
        a0 += bf_lo(v3.x); a1 += bf_hi(v3.x); a2 += bf_lo(v3.y); a3 += bf_hi(v3.y);
    }
    for (; j + 1 < end; j += 2) {
        int s0 = csr[j + half];
        uint2 v0 = T2[(size_t)s0 * 32 + li];
        a0 += bf_lo(v0.x); a1 += bf_hi(v0.x); a2 += bf_lo(v0.y); a3 += bf_hi(v0.y);
    }
    if (j < end && half == 0) {
        int s0 = csr[j];
        uint2 v0 = T2[(size_t)s0 * 32 + li];
        a0 += bf_lo(v0.x); a1 += bf_hi(v0.x); a2 += bf_lo(v0.y); a3 += bf_hi(v0.y);
    }
    a0 += __shfl_xor(a0, 32);
    a1 += __shfl_xor(a1, 32);
    a2 += __shfl_xor(a2, 32);
    a3 += __shfl_xor(a3, 32);
    if (half == 0) {
        float di = dinv[d];
        uint2 vd = T2[(size_t)d * 32 + li];
        float4 bs = *(const float4*)&bias[4 * li];
        float v0 = di * (a0 + bf_lo(vd.x)) + bs.x;
        float v1 = di * (a1 + bf_hi(vd.x)) + bs.y;
        float v2 = di * (a2 + bf_lo(vd.y)) + bs.z;
        float v3 = di * (a3 + bf_hi(vd.y)) + bs.w;
        s4[0] += v0; s4[1] += v1; s4[2] += v2; s4[3] += v3;
        q4[0] += v0 * v0; q4[1] += v1 * v1; q4[2] += v2 * v2; q4[3] += v3 * v3;
        ushort4 o;
        o.x = f2bf(v0); o.y = f2bf(v1); o.z = f2bf(v2); o.w = f2bf(v3);
        *(ushort4*)&Ah[(size_t)d * HD + 4 * li] = o;
    }
}

// ---------------- phase: MLP head (one graph per block) ----------------
static __device__ __forceinline__ void mlp_body(int b, const float* pooled,
                                                const int* batch, const float* gfeat,
                                                const float* M1w, const float* M1b,
                                                const float* M2w, const float* M2b,
                                                const float* M3w, const float* M3b,
                                                float* out, char* smem) {
    int* sb = (int*)smem;
    float* z = (float*)(smem + 16);
    float* z1 = z + HD + GD;
    float* z2 = z1 + MD;
    int t = threadIdx.x;
    if (t < 2) {
        int val = b + t;
        int lo = 0, hi = NN;
        while (lo < hi) {
            int mid = (lo + hi) >> 1;
            if (batch[mid] < val) lo = mid + 1; else hi = mid;
        }
        sb[t] = lo;
    }
    __syncthreads();
    float ic = 1.f / fmaxf((float)(sb[1] - sb[0]), 1.f);
    if (t < HD) z[t] = pooled[(size_t)b * HD + t] * ic;
    else if (t < HD + GD) z[t] = gfeat[b * GD + (t - HD)];
    __syncthreads();
    if (t < MD) {
        float a = M1b[t];
        for (int k = 0; k < HD + GD; ++k) a += z[k] * M1w[k * MD + t];
        z1[t] = fmaxf(a, 0.f);
    }
    __syncthreads();
    if (t < MD / 2) {
        float a2 = M2b[t];
        for (int k = 0; k < MD; ++k) a2 += z1[k] * M2w[k * (MD / 2) + t];
        z2[t] = fmaxf(a2, 0.f);
    }
    __syncthreads();
    if (t < 64) {
        float p = z2[t] * M3w[t];
#pragma unroll
        for (int off = 32; off; off >>= 1) p += __shfl_down(p, off);
        if (t == 0) out[b] = p + M3b[0];
    }
}

// ---------------- the mega-kernel: 9 grid syncs, 1 dispatch ----------------
__global__ __launch_bounds__(256, 2) void k_mega(
    const float* __restrict__ x, const int* __restrict__ src, const int* __restrict__ dst,
    const int* __restrict__ batch, const float* __restrict__ gfeat,
    const float* __restrict__ W0, const float* __restrict__ W1, const float* __restrict__ W2,
    const float* __restrict__ b0, const float* __restrict__ b1, const float* __restrict__ b2,
    const float* __restrict__ g0, const float* __restrict__ g1, const float* __restrict__ g2,
    const float* __restrict__ be0, const float* __restrict__ be1, const float* __restrict__ be2,
    const float* __restrict__ M1w, const float* __restrict__ M1b,
    const float* __restrict__ M2w, const float* __restrict__ M2b,
    const float* __restrict__ M3w, const float* __restrict__ M3b,
    float* __restrict__ out,
    int* bucket_cnt, float* pooled, float* stats,
    int* offsets, int* csr, float* dinv,
    unsigned short* Wt, unsigned* binned,
    unsigned short* Ah, unsigned short* Th, unsigned* bar) {
    __shared__ __align__(16) char smem[SMEMB];
    int bx = blockIdx.x;

    // P1: bin edges
    if (bx < BINB) bin_body(bx, src, dst, bucket_cnt, binned, smem);
    gsync(bar);

    // P2: CSR + W transpose
    if (bx < NBK + 3)
        csr_body(bx, binned, bucket_cnt, offsets, dinv, csr, W0, W1, W2, Wt, smem);
    gsync(bar);

    const uint2* T2 = (const uint2*)Th;
#pragma unroll
    for (int L = 0; L < 3; ++L) {
        const unsigned short* WtgL = Wt + (size_t)L * 16384;
        const float* stIn = (L == 0) ? stats : stats + (L - 1) * 256;
        const float* gIn = (L == 1) ? g0 : g1;
        const float* beIn = (L == 1) ? be0 : be1;
        // gemm phase
        for (int vb = bx; vb < GEMMV; vb += GRID)
            gemm_body(vb, x, Ah, WtgL, Th, stIn, gIn, beIn, dinv, L > 0, smem);
        gsync(bar);
        // aggregate phase + fused column stats
        {
            const float* biasL = (L == 0) ? b0 : ((L == 1) ? b1 : b2);
            float* statsL = stats + L * 256;
            f32x4 s4 = {0.f, 0.f, 0.f, 0.f}, q4 = {0.f, 0.f, 0.f, 0.f};
            for (int vb = bx; vb < AGGV; vb += GRID)
                agg_body(vb, T2, offsets, csr, dinv, biasL, Ah, s4, q4);
            float4* lsum = (float4*)smem;
            float4* lq = (float4*)(smem + 4096);
            __syncthreads();
            float4 ws; ws.x = s4[0]; ws.y = s4[1]; ws.z = s4[2]; ws.w = s4[3];
            float4 wq; wq.x = q4[0]; wq.y = q4[1]; wq.z = q4[2]; wq.w = q4[3];
            lsum[threadIdx.x] = ws;
            lq[threadIdx.x] = wq;
            __syncthreads();
            int t = threadIdx.x;
            if (t < 32) {
                float4 a = lsum[t], bb_ = lsum[64 + t], cc = lsum[128 + t], dd = lsum[192 + t];
                atomicAdd(&statsL[4 * t + 0], a.x + bb_.x + cc.x + dd.x);
                atomicAdd(&statsL[4 * t + 1], a.y + bb_.y + cc.y + dd.y);
                atomicAdd(&statsL[4 * t + 2], a.z + bb_.z + cc.z + dd.z);
                atomicAdd(&statsL[4 * t + 3], a.w + bb_.w + cc.w + dd.w);
            } else if (t >= 64 && t < 96) {
                int u = t - 64;
                float4 a = lq[u], bb_ = lq[64 + u], cc = lq[128 + u], dd = lq[192 + u];
                atomicAdd(&statsL[128 + 4 * u + 0], a.x + bb_.x + cc.x + dd.x);
                atomicAdd(&statsL[128 + 4 * u + 1], a.y + bb_.y + cc.y + dd.y);
                atomicAdd(&statsL[128 + 4 * u + 2], a.z + bb_.z + cc.z + dd.z);
                atomicAdd(&statsL[128 + 4 * u + 3], a.w + bb_.w + cc.w + dd.w);
            }
        }
        gsync(bar);
    }

    // P: pool (inline BN of layer 2 from stats)
    {
        float* ssP = (float*)smem;
        int t = threadIdx.x;
        ssP[t] = stats[512 + t];
        __syncthreads();
        if (t < 128) {
            float mu = ssP[t] * (1.f / NN);
            float var = ssP[128 + t] * (1.f / NN) - mu * mu;
            float sc = g2[t] * rsqrtf(var + EPSV);
            float sh = be2[t] - mu * sc;
            ssP[t] = sc;
            ssP[128 + t] = sh;
        }
        __syncthreads();
        int fu = t & 63;
        int half = t >> 6;
        float s0 = ssP[2 * fu], s1 = ssP[2 * fu + 1];
        float h0 = ssP[128 + 2 * fu], h1 = ssP[128 + 2 * fu + 1];
        const unsigned* Au = (const unsigned*)Ah;
        for (int vb = bx; vb < POOLV; vb += GRID) {
            int r0 = vb * 64;
            int rend = min(r0 + 64, NN);
            float a0 = 0.f, a1 = 0.f;
            int cg = -1;
            for (int r = r0 + half; r < rend; r += 4) {
                int g = batch[r];
                if (g != cg) {
                    if (cg >= 0) {
                        atomicAdd(&pooled[(size_t)cg * HD + 2 * fu], a0);
                        atomicAdd(&pooled[(size_t)cg * HD + 2 * fu + 1], a1);
                    }
                    cg = g;
                    a0 = 0.f; a1 = 0.f;
                }
                unsigned v = Au[(size_t)r * 64 + fu];
                a0 += fmaxf(bf_lo(v) * s0 + h0, 0.f);
                a1 += fmaxf(bf_hi(v) * s1 + h1, 0.f);
            }
            if (cg >= 0) {
                atomicAdd(&pooled[(size_t)cg * HD + 2 * fu], a0);
                atomicAdd(&pooled[(size_t)cg * HD + 2 * fu + 1], a1);
            }
        }
    }
    gsync(bar);

    // P: MLP head — GRID == BG, one graph per block
    if (bx < BG)
        mlp_body(bx, pooled, batch, gfeat, M1w, M1b, M2w, M2b, M3w, M3b, out, smem);
}

static inline size_t alg(size_t x) { return (x + 255) & ~(size_t)255; }

extern "C" void kernel_launch(void* const* d_in, const int* in_sizes, int n_in,
                              void* d_out, int out_size, void* d_ws, size_t ws_size,
                              hipStream_t stream) {
    const float* x = (const float*)d_in[0];
    const int* ei = (const int*)d_in[1];
    const int* batch = (const int*)d_in[2];
    const float* gf = (const float*)d_in[3];
    const float* W[3] = {(const float*)d_in[4], (const float*)d_in[8], (const float*)d_in[12]};
    const float* bb[3] = {(const float*)d_in[5], (const float*)d_in[9], (const float*)d_in[13]};
    const float* gg[3] = {(const float*)d_in[6], (const float*)d_in[10], (const float*)d_in[14]};
    const float* be[3] = {(const float*)d_in[7], (const float*)d_in[11], (const float*)d_in[15]};
    const float* M1w = (const float*)d_in[16];
    const float* M1b = (const float*)d_in[17];
    const float* M2w = (const float*)d_in[18];
    const float* M2b = (const float*)d_in[19];
    const float* M3w = (const float*)d_in[20];
    const float* M3b = (const float*)d_in[21];
    float* out = (float*)d_out;

    char* w = (char*)d_ws;
    int* bucket_cnt = (int*)w;    w += alg((size_t)NBK * 4);
    float* pooled = (float*)w;    w += alg((size_t)BG * HD * 4);
    float* stats = (float*)w;     w += alg((size_t)3 * 256 * 4);
    unsigned* bar = (unsigned*)w; w += alg((size_t)64);
    int* offsets = (int*)w;       w += alg((size_t)(NN + 1) * 4);
    int* csr = (int*)w;           w += alg((size_t)NE * 4);
    float* dinv = (float*)w;      w += alg((size_t)NN * 4);
    unsigned short* Wt = (unsigned short*)w;  w += alg((size_t)3 * 16384 * 2);
    unsigned* binned = (unsigned*)w;          w += alg((size_t)NBK * BCAP * 4);
    unsigned short* Ah = (unsigned short*)w;  w += alg((size_t)NN * HD * 2);
    unsigned short* Th = (unsigned short*)w;  w += alg((size_t)NN * HD * 2);

    const int* src = ei;
    const int* dst = ei + NE;

    k_init<<<256, 256, 0, stream>>>(bucket_cnt, pooled, stats, bar);
    k_mega<<<GRID, 256, 0, stream>>>(x, src, dst, batch, gf,
                                     W[0], W[1], W[2], bb[0], bb[1], bb[2],
                                     gg[0], gg[1], gg[2], be[0], be[1], be[2],
                                     M1w, M1b, M2w, M2b, M3w, M3b, out,
                                     bucket_cnt, pooled, stats, offsets, csr, dinv,
                                     Wt, binned, Ah, Th, bar);
}